// Round 1
// baseline (1491.820 us; speedup 1.0000x reference)
//
#include <hip/hip_runtime.h>

// 2-layer GCN, N=1M nodes, E=4M edges (+self-loops), 4 -> 16 -> 2 features.
// Normalization commuted with weight matmuls so edge scatter is 4 floats (L1)
// and 2 floats (L2) per edge instead of 16/2 on the post-matmul features.

__global__ void k_init_deg(float* __restrict__ deg, int n) {
    int i = blockIdx.x * blockDim.x + threadIdx.x;
    if (i < n) deg[i] = 1.0f;  // self-loop contributes 1 to in-degree
}

__global__ void k_count_deg(const int* __restrict__ dst, int E, float* __restrict__ deg) {
    int e = blockIdx.x * blockDim.x + threadIdx.x;
    if (e < E) atomicAdd(&deg[dst[e]], 1.0f);
}

__global__ void k_rsqrt(float* __restrict__ deg, int n) {
    int i = blockIdx.x * blockDim.x + threadIdx.x;
    if (i < n) deg[i] = rsqrtf(deg[i]);  // deg >= 1 always
}

// agg1[i] = x[i] * dinv[i]^2   (self-loop term of layer-1 aggregation)
__global__ void k_self1(const float4* __restrict__ x, const float* __restrict__ dinv,
                        float4* __restrict__ agg1, int n) {
    int i = blockIdx.x * blockDim.x + threadIdx.x;
    if (i < n) {
        float d = dinv[i];
        float s = d * d;
        float4 v = x[i];
        agg1[i] = make_float4(v.x * s, v.y * s, v.z * s, v.w * s);
    }
}

// agg1[dst] += x[src] * dinv[src]*dinv[dst]   (4 floats per edge)
__global__ void k_edge1(const int* __restrict__ src, const int* __restrict__ dst,
                        const float* __restrict__ dinv, const float4* __restrict__ x,
                        float* __restrict__ agg1, int E) {
    int e = blockIdx.x * blockDim.x + threadIdx.x;
    if (e < E) {
        int s = src[e], d = dst[e];
        float nrm = dinv[s] * dinv[d];
        float4 v = x[s];
        float* p = agg1 + 4 * (size_t)d;
        atomicAdd(p + 0, v.x * nrm);
        atomicAdd(p + 1, v.y * nrm);
        atomicAdd(p + 2, v.z * nrm);
        atomicAdd(p + 3, v.w * nrm);
    }
}

// Fused per-node: h = relu(agg1 @ W1 + b1); h2 = h @ W2;
// store h2 and agg2 self-term h2 * dinv^2.
__global__ void k_mid(const float4* __restrict__ agg1, const float* __restrict__ dinv,
                      const float* __restrict__ W1, const float* __restrict__ b1,
                      const float* __restrict__ W2,
                      float2* __restrict__ h2, float2* __restrict__ agg2, int n) {
    int i = blockIdx.x * blockDim.x + threadIdx.x;
    if (i >= n) return;
    float4 a = agg1[i];
    float g0 = 0.f, g1 = 0.f;
#pragma unroll
    for (int k = 0; k < 16; ++k) {
        float h = a.x * W1[k] + a.y * W1[16 + k] + a.z * W1[32 + k] + a.w * W1[48 + k] + b1[k];
        h = fmaxf(h, 0.f);
        g0 += h * W2[2 * k];
        g1 += h * W2[2 * k + 1];
    }
    float d = dinv[i];
    float s = d * d;
    h2[i]   = make_float2(g0, g1);
    agg2[i] = make_float2(g0 * s, g1 * s);
}

// agg2[dst] += h2[src] * norm   (2 floats per edge)
__global__ void k_edge2(const int* __restrict__ src, const int* __restrict__ dst,
                        const float* __restrict__ dinv, const float2* __restrict__ h2,
                        float* __restrict__ agg2, int E) {
    int e = blockIdx.x * blockDim.x + threadIdx.x;
    if (e < E) {
        int s = src[e], d = dst[e];
        float nrm = dinv[s] * dinv[d];
        float2 v = h2[s];
        float* p = agg2 + 2 * (size_t)d;
        atomicAdd(p + 0, v.x * nrm);
        atomicAdd(p + 1, v.y * nrm);
    }
}

__global__ void k_final(const float2* __restrict__ agg2, const float* __restrict__ b2,
                        float2* __restrict__ out, int n) {
    int i = blockIdx.x * blockDim.x + threadIdx.x;
    if (i >= n) return;
    float2 a = agg2[i];
    float o0 = a.x + b2[0], o1 = a.y + b2[1];
    float m = fmaxf(o0, o1);
    float l = m + logf(expf(o0 - m) + expf(o1 - m));
    out[i] = make_float2(o0 - l, o1 - l);
}

extern "C" void kernel_launch(void* const* d_in, const int* in_sizes, int n_in,
                              void* d_out, int out_size, void* d_ws, size_t ws_size,
                              hipStream_t stream) {
    const float* x  = (const float*)d_in[0];
    const int*   ei = (const int*)d_in[1];   // [2, E] int32, row-major: src then dst
    const float* W1 = (const float*)d_in[3]; // [4,16]
    const float* b1 = (const float*)d_in[4]; // [16]
    const float* W2 = (const float*)d_in[5]; // [16,2]
    const float* b2 = (const float*)d_in[6]; // [2]

    const int N = in_sizes[0] / 4;
    const int E = in_sizes[1] / 2;
    const int* src = ei;
    const int* dst = ei + E;

    // Workspace layout (floats): dinv[N] | agg1[4N] | h2[2N] | agg2[2N] = 9N floats = 36 MB
    float* dinv = (float*)d_ws;
    float* agg1 = dinv + N;
    float* h2   = agg1 + 4 * (size_t)N;
    float* agg2 = h2 + 2 * (size_t)N;

    const int B = 256;
    const int gN = (N + B - 1) / B;
    const int gE = (E + B - 1) / B;

    k_init_deg<<<gN, B, 0, stream>>>(dinv, N);
    k_count_deg<<<gE, B, 0, stream>>>(dst, E, dinv);
    k_rsqrt<<<gN, B, 0, stream>>>(dinv, N);
    k_self1<<<gN, B, 0, stream>>>((const float4*)x, dinv, (float4*)agg1, N);
    k_edge1<<<gE, B, 0, stream>>>(src, dst, dinv, (const float4*)x, agg1, E);
    k_mid<<<gN, B, 0, stream>>>((const float4*)agg1, dinv, W1, b1, W2,
                                (float2*)h2, (float2*)agg2, N);
    k_edge2<<<gE, B, 0, stream>>>(src, dst, dinv, (const float2*)h2, agg2, E);
    k_final<<<gN, B, 0, stream>>>((const float2*)agg2, b2, (float2*)d_out, N);
}

// Round 3
// 518.588 us; speedup vs baseline: 2.8767x; 2.8767x over previous
//
#include <hip/hip_runtime.h>

// 2-layer GCN, N=1M nodes, E=4M edges (+self-loops folded in algebraically),
// 4 -> 16 -> 2 features. Pull-based CSR aggregation (built per call) replaces
// per-edge float atomics: 28M scattered atomics -> 4M int atomics + gathers.
//
// Math: agg1[i] = dinv[i]*(x[i]*dinv[i] + sum_{s in nbr(i)} x[s]*dinv[s])
//       h2d[i]  = (relu(agg1@W1+b1)@W2) * dinv[i]
//       out[i]  = log_softmax(dinv[i]*(h2d[i] + sum h2d[s]) + b2)

typedef unsigned int u32;
typedef unsigned short u16;

// pos[e] = slot of edge e within dst's list; cnt[d] = in-degree (no self-loop)
__global__ void k_hist(const int* __restrict__ dst, int E,
                       u32* __restrict__ cnt, u16* __restrict__ pos) {
    int e = blockIdx.x * blockDim.x + threadIdx.x;
    if (e < E) {
        u32 p = atomicAdd(&cnt[dst[e]], 1u);
        pos[e] = (u16)p;
    }
}

// Chunked exclusive scan of cnt -> off, block base via one global atomic
// (block ordering arbitrary: any disjoint partition of [0,E) is a valid CSR).
// Also emits dinv[i] = rsqrt(cnt[i]+1)  (+1 = self-loop).
__global__ void k_scan(const u32* __restrict__ cnt, u32* __restrict__ off,
                       float* __restrict__ dinv, u32* __restrict__ gcount, int n) {
    __shared__ u32 sdata[256];
    __shared__ u32 bbase;
    const int tid = threadIdx.x;
    const int base = blockIdx.x * 1024 + tid * 4;
    u32 c0 = 0, c1 = 0, c2 = 0, c3 = 0;
    if (base + 0 < n) c0 = cnt[base + 0];
    if (base + 1 < n) c1 = cnt[base + 1];
    if (base + 2 < n) c2 = cnt[base + 2];
    if (base + 3 < n) c3 = cnt[base + 3];
    u32 s = c0 + c1 + c2 + c3;
    sdata[tid] = s;
    __syncthreads();
    // Hillis-Steele inclusive scan over 256 threads
    for (int d = 1; d < 256; d <<= 1) {
        u32 v = (tid >= d) ? sdata[tid - d] : 0u;
        __syncthreads();
        sdata[tid] += v;
        __syncthreads();
    }
    u32 incl = sdata[tid];
    u32 excl = incl - s;
    if (tid == 255) bbase = atomicAdd(gcount, incl);  // incl == block total at tid 255
    __syncthreads();
    u32 o = bbase + excl;
    if (base + 0 < n) { off[base + 0] = o;                dinv[base + 0] = rsqrtf((float)(c0 + 1)); }
    if (base + 1 < n) { off[base + 1] = o + c0;           dinv[base + 1] = rsqrtf((float)(c1 + 1)); }
    if (base + 2 < n) { off[base + 2] = o + c0 + c1;      dinv[base + 2] = rsqrtf((float)(c2 + 1)); }
    if (base + 3 < n) { off[base + 3] = o + c0 + c1 + c2; dinv[base + 3] = rsqrtf((float)(c3 + 1)); }
}

__global__ void k_scatter(const int* __restrict__ src, const int* __restrict__ dst,
                          const u32* __restrict__ off, const u16* __restrict__ pos,
                          u32* __restrict__ csr, int E) {
    int e = blockIdx.x * blockDim.x + threadIdx.x;
    if (e < E) {
        int d = dst[e];
        csr[off[d] + (u32)pos[e]] = (u32)src[e];
    }
}

// Layer 1 pull + fused W1/relu/W2: writes h2d[i] = h2[i]*dinv[i] (float2)
__global__ void k_pull1(const u32* __restrict__ off, const u32* __restrict__ cnt,
                        const float* __restrict__ dinv, const u32* __restrict__ csr,
                        const float4* __restrict__ x,
                        const float* __restrict__ W1, const float* __restrict__ b1,
                        const float* __restrict__ W2,
                        float2* __restrict__ h2d, int n) {
    int i = blockIdx.x * blockDim.x + threadIdx.x;
    if (i >= n) return;
    const u32 o = off[i];
    const u32 c = cnt[i];
    const float di = dinv[i];
    float4 xi = x[i];
    float ax = xi.x * di, ay = xi.y * di, az = xi.z * di, aw = xi.w * di;  // self term
    for (u32 k = 0; k < c; ++k) {
        u32 sidx = csr[o + k];
        float ds = dinv[sidx];
        float4 v = x[sidx];
        ax += v.x * ds; ay += v.y * ds; az += v.z * ds; aw += v.w * ds;
    }
    ax *= di; ay *= di; az *= di; aw *= di;  // agg1[i]
    float g0 = 0.f, g1 = 0.f;
#pragma unroll
    for (int k = 0; k < 16; ++k) {
        float h = ax * W1[k] + ay * W1[16 + k] + az * W1[32 + k] + aw * W1[48 + k] + b1[k];
        h = fmaxf(h, 0.f);
        g0 += h * W2[2 * k];
        g1 += h * W2[2 * k + 1];
    }
    h2d[i] = make_float2(g0 * di, g1 * di);
}

// Layer 2 pull + fused log_softmax (2 classes)
__global__ void k_pull2(const u32* __restrict__ off, const u32* __restrict__ cnt,
                        const float* __restrict__ dinv, const u32* __restrict__ csr,
                        const float2* __restrict__ h2d, const float* __restrict__ b2,
                        float2* __restrict__ out, int n) {
    int i = blockIdx.x * blockDim.x + threadIdx.x;
    if (i >= n) return;
    const u32 o = off[i];
    const u32 c = cnt[i];
    const float di = dinv[i];
    float2 self = h2d[i];
    float a0 = self.x, a1 = self.y;
    for (u32 k = 0; k < c; ++k) {
        u32 sidx = csr[o + k];
        float2 v = h2d[sidx];
        a0 += v.x; a1 += v.y;
    }
    float g0 = a0 * di + b2[0];
    float g1 = a1 * di + b2[1];
    float m = fmaxf(g0, g1);
    float l = m + logf(expf(g0 - m) + expf(g1 - m));
    out[i] = make_float2(g0 - l, g1 - l);
}

extern "C" void kernel_launch(void* const* d_in, const int* in_sizes, int n_in,
                              void* d_out, int out_size, void* d_ws, size_t ws_size,
                              hipStream_t stream) {
    const float* x  = (const float*)d_in[0];
    const int*   ei = (const int*)d_in[1];   // [2, E] int32: src row then dst row
    const float* W1 = (const float*)d_in[3];
    const float* b1 = (const float*)d_in[4];
    const float* W2 = (const float*)d_in[5];
    const float* b2 = (const float*)d_in[6];

    const int N = in_sizes[0] / 4;
    const int E = in_sizes[1] / 2;
    const int* src = ei;
    const int* dst = ei + E;

    // Workspace layout (bytes), total exactly 36,000,000 for N=1e6/E=4e6:
    //   off  [N u32]              @ 0
    //   cnt  [N u32]              @ 4N
    //   dinv [N f32]              @ 8N
    //   pos  [E u16] / h2d [2N f32] @ 12N   (pos dead after scatter; reused)
    //   csr  [E u32]              @ 12N + 2E   (first 4B doubles as scan gcount pre-scatter)
    char* w = (char*)d_ws;
    u32*   off  = (u32*)(w);
    u32*   cnt  = (u32*)(w + 4 * (size_t)N);
    float* dinv = (float*)(w + 8 * (size_t)N);
    u16*   pos  = (u16*)(w + 12 * (size_t)N);
    float2* h2d = (float2*)(w + 12 * (size_t)N);
    u32*   csr  = (u32*)(w + 12 * (size_t)N + 2 * (size_t)E);
    u32*   gcount = csr;  // borrow csr[0] until k_scatter runs

    const int B = 256;
    const int gE = (E + B - 1) / B;
    const int gN = (N + B - 1) / B;
    const int gS = (N + 1023) / 1024;

    hipMemsetAsync(cnt, 0, 4 * (size_t)N, stream);
    hipMemsetAsync(gcount, 0, 4, stream);
    k_hist<<<gE, B, 0, stream>>>(dst, E, cnt, pos);
    k_scan<<<gS, B, 0, stream>>>(cnt, off, dinv, gcount, N);
    k_scatter<<<gE, B, 0, stream>>>(src, dst, off, pos, csr, E);
    k_pull1<<<gN, B, 0, stream>>>(off, cnt, dinv, csr, (const float4*)x, W1, b1, W2, h2d, N);
    k_pull2<<<gN, B, 0, stream>>>(off, cnt, dinv, csr, h2d, b2, (float2*)d_out, N);
}

// Round 6
// 332.272 us; speedup vs baseline: 4.4898x; 1.5607x over previous
//
#include <hip/hip_runtime.h>

// 2-layer GCN via bucketed (counting-sort) aggregation with LDS-privatized
// accumulators. Nodes are grouped into buckets of 2048 so per-bucket float
// accumulators fit in LDS; per-edge work is: coalesced record read + one
// cache-hot gather + LDS atomic adds. No per-node global atomics anywhere.
//
// Math (normalization commuted through the linear layers):
//   agg1[i] = dinv[i]*(x[i]*dinv[i] + sum_{s->i} x[s]*dinv[s])
//   h2d[i]  = (relu(agg1@W1+b1)@W2) * dinv[i]
//   out[i]  = log_softmax(dinv[i]*(h2d[i] + sum_{s->i} h2d[s]) + b2)

typedef unsigned int u32;

#define BSHIFT 11            // 2048 nodes per bucket
#define BNODES 2048
#define MAXNB 512            // max buckets supported (N <= 2^20)
#define EPB 16384            // edges per block in binning kernels

// ---- Phase A1: count edges per bucket (LDS-privatized) ----
__global__ void k_bincount(const int* __restrict__ dst, int E, int NB,
                           u32* __restrict__ bucketTotal) {
    __shared__ u32 h[MAXNB];
    const int tid = threadIdx.x;
    for (int j = tid; j < MAXNB; j += 256) h[j] = 0;
    __syncthreads();
    const int start = blockIdx.x * EPB;
    const int end = min(start + EPB, E);
    for (int e = start + tid; e < end; e += 256)
        atomicAdd(&h[((u32)dst[e]) >> BSHIFT], 1u);
    __syncthreads();
    for (int j = tid; j < NB; j += 256)
        if (h[j]) atomicAdd(&bucketTotal[j], h[j]);
}

// ---- Phase A2: exclusive scan of bucket totals (single block) ----
__global__ void k_bucketscan(const u32* __restrict__ bucketTotal,
                             u32* __restrict__ bucketBase,
                             u32* __restrict__ cursor, int NB, int E) {
    __shared__ u32 s[MAXNB];
    const int tid = threadIdx.x;  // 512 threads
    u32 v = (tid < NB) ? bucketTotal[tid] : 0u;
    s[tid] = v;
    __syncthreads();
    for (int d = 1; d < MAXNB; d <<= 1) {
        u32 t = (tid >= d) ? s[tid - d] : 0u;
        __syncthreads();
        s[tid] += t;
        __syncthreads();
    }
    u32 excl = s[tid] - v;
    if (tid < NB) { bucketBase[tid] = excl; cursor[tid] = excl; }
    if (tid == 0) bucketBase[NB] = (u32)E;
}

// ---- Phase A3: scatter edges into bucket-grouped records ----
// rec = src | (dstLocal << 20)   (src < 2^20, dstLocal < 2^11)
__global__ void k_binscatter(const int* __restrict__ src, const int* __restrict__ dst,
                             int E, int NB, u32* __restrict__ cursor,
                             u32* __restrict__ rec) {
    __shared__ u32 h[MAXNB];
    const int tid = threadIdx.x;
    for (int j = tid; j < MAXNB; j += 256) h[j] = 0;
    __syncthreads();
    const int start = blockIdx.x * EPB;
    const int end = min(start + EPB, E);
    for (int e = start + tid; e < end; e += 256)
        atomicAdd(&h[((u32)dst[e]) >> BSHIFT], 1u);
    __syncthreads();
    // reserve contiguous per-bin range for this block; h[j] becomes write cursor
    for (int j = tid; j < NB; j += 256) {
        u32 c = h[j];
        h[j] = c ? atomicAdd(&cursor[j], c) : 0u;
    }
    __syncthreads();
    for (int e = start + tid; e < end; e += 256) {
        u32 d = (u32)dst[e];
        u32 b = d >> BSHIFT;
        u32 slot = atomicAdd(&h[b], 1u);
        rec[slot] = ((u32)src[e]) | ((d & (BNODES - 1u)) << 20);
    }
}

// ---- Phase C: per-bucket degree -> dinv ----
__global__ void k_deg(const u32* __restrict__ rec, const u32* __restrict__ bucketBase,
                      float* __restrict__ dinv, int N) {
    __shared__ u32 deg[BNODES];
    const int tid = threadIdx.x;  // 256
    const int b = blockIdx.x;
    for (int j = tid; j < BNODES; j += 256) deg[j] = 0;
    __syncthreads();
    const u32 s0 = bucketBase[b], s1 = bucketBase[b + 1];
    for (u32 i = s0 + tid; i < s1; i += 256)
        atomicAdd(&deg[rec[i] >> 20], 1u);
    __syncthreads();
    const int nodeBase = b << BSHIFT;
    for (int n = tid; n < BNODES; n += 256) {
        int gn = nodeBase + n;
        if (gn < N) dinv[gn] = rsqrtf((float)(deg[n] + 1u));
    }
}

// ---- Phase D: layer-1 aggregate (LDS) + fused W1/relu/W2 -> h2d ----
__global__ void k_l1(const u32* __restrict__ rec, const u32* __restrict__ bucketBase,
                     const float* __restrict__ dinv, const float4* __restrict__ x,
                     const float* __restrict__ W1, const float* __restrict__ b1,
                     const float* __restrict__ W2,
                     float2* __restrict__ h2d, int N) {
    __shared__ float agg[BNODES * 4];
    const int tid = threadIdx.x;  // 1024
    const int b = blockIdx.x;
    for (int j = tid; j < BNODES * 4; j += 1024) agg[j] = 0.f;
    __syncthreads();
    const u32 s0 = bucketBase[b], s1 = bucketBase[b + 1];
    for (u32 i = s0 + tid; i < s1; i += 1024) {
        u32 r = rec[i];
        u32 s = r & 0xFFFFFu;
        u32 dl = r >> 20;
        float ds = dinv[s];
        float4 v = x[s];
        atomicAdd(&agg[dl * 4 + 0], v.x * ds);
        atomicAdd(&agg[dl * 4 + 1], v.y * ds);
        atomicAdd(&agg[dl * 4 + 2], v.z * ds);
        atomicAdd(&agg[dl * 4 + 3], v.w * ds);
    }
    __syncthreads();
    const int nodeBase = b << BSHIFT;
    for (int n = tid; n < BNODES; n += 1024) {
        int gn = nodeBase + n;
        if (gn >= N) continue;
        float di = dinv[gn];
        float4 xi = x[gn];
        float ax = (xi.x * di + agg[n * 4 + 0]) * di;
        float ay = (xi.y * di + agg[n * 4 + 1]) * di;
        float az = (xi.z * di + agg[n * 4 + 2]) * di;
        float aw = (xi.w * di + agg[n * 4 + 3]) * di;
        float g0 = 0.f, g1 = 0.f;
#pragma unroll
        for (int k = 0; k < 16; ++k) {
            float h = ax * W1[k] + ay * W1[16 + k] + az * W1[32 + k] + aw * W1[48 + k] + b1[k];
            h = fmaxf(h, 0.f);
            g0 += h * W2[2 * k];
            g1 += h * W2[2 * k + 1];
        }
        h2d[gn] = make_float2(g0 * di, g1 * di);
    }
}

// ---- Phase E: layer-2 aggregate (LDS) + fused log_softmax ----
__global__ void k_l2(const u32* __restrict__ rec, const u32* __restrict__ bucketBase,
                     const float* __restrict__ dinv, const float2* __restrict__ h2d,
                     const float* __restrict__ b2, float2* __restrict__ out, int N) {
    __shared__ float agg[BNODES * 2];
    const int tid = threadIdx.x;  // 1024
    const int b = blockIdx.x;
    for (int j = tid; j < BNODES * 2; j += 1024) agg[j] = 0.f;
    __syncthreads();
    const u32 s0 = bucketBase[b], s1 = bucketBase[b + 1];
    for (u32 i = s0 + tid; i < s1; i += 1024) {
        u32 r = rec[i];
        u32 s = r & 0xFFFFFu;
        u32 dl = r >> 20;
        float2 v = h2d[s];
        atomicAdd(&agg[dl * 2 + 0], v.x);
        atomicAdd(&agg[dl * 2 + 1], v.y);
    }
    __syncthreads();
    const int nodeBase = b << BSHIFT;
    for (int n = tid; n < BNODES; n += 1024) {
        int gn = nodeBase + n;
        if (gn >= N) continue;
        float di = dinv[gn];
        float2 self = h2d[gn];
        float g0 = (self.x + agg[n * 2 + 0]) * di + b2[0];
        float g1 = (self.y + agg[n * 2 + 1]) * di + b2[1];
        float m = fmaxf(g0, g1);
        float l = m + logf(expf(g0 - m) + expf(g1 - m));
        out[gn] = make_float2(g0 - l, g1 - l);
    }
}

extern "C" void kernel_launch(void* const* d_in, const int* in_sizes, int n_in,
                              void* d_out, int out_size, void* d_ws, size_t ws_size,
                              hipStream_t stream) {
    const float* x  = (const float*)d_in[0];
    const int*   ei = (const int*)d_in[1];   // [2, E] int32: src row then dst row
    const float* W1 = (const float*)d_in[3];
    const float* b1 = (const float*)d_in[4];
    const float* W2 = (const float*)d_in[5];
    const float* b2 = (const float*)d_in[6];

    const int N = in_sizes[0] / 4;
    const int E = in_sizes[1] / 2;
    const int* src = ei;
    const int* dst = ei + E;
    const int NB = (N + BNODES - 1) >> BSHIFT;  // 489 for N=1e6

    // Workspace (bytes): rec E*4 =16MB | dinv N*4 =4MB | h2d N*8 =8MB | bins ~6KB
    char* w = (char*)d_ws;
    u32*    rec  = (u32*)(w);
    float*  dinv = (float*)(w + 4 * (size_t)E);
    float2* h2d  = (float2*)(w + 4 * (size_t)E + 4 * (size_t)N);
    u32*    bucketTotal = (u32*)(w + 4 * (size_t)E + 12 * (size_t)N);
    u32*    bucketBase  = bucketTotal + MAXNB;        // NB+1 entries
    u32*    cursor      = bucketBase + MAXNB + 1;

    const int gA = (E + EPB - 1) / EPB;  // 245

    hipMemsetAsync(bucketTotal, 0, sizeof(u32) * (size_t)NB, stream);
    k_bincount<<<gA, 256, 0, stream>>>(dst, E, NB, bucketTotal);
    k_bucketscan<<<1, MAXNB, 0, stream>>>(bucketTotal, bucketBase, cursor, NB, E);
    k_binscatter<<<gA, 256, 0, stream>>>(src, dst, E, NB, cursor, rec);
    k_deg<<<NB, 256, 0, stream>>>(rec, bucketBase, dinv, N);
    k_l1<<<NB, 1024, 0, stream>>>(rec, bucketBase, dinv, (const float4*)x, W1, b1, W2, h2d, N);
    k_l2<<<NB, 1024, 0, stream>>>(rec, bucketBase, dinv, h2d, b2, (float2*)d_out, N);
}

// Round 7
// 332.173 us; speedup vs baseline: 4.4911x; 1.0003x over previous
//
#include <hip/hip_runtime.h>

// 2-layer GCN via bucketed (counting-sort) aggregation with LDS-privatized
// accumulators. Round-7 changes vs round-6:
//  - xd[s] = x[s]*dinv[s] precomputed (fused into k_deg) as packed bf16x4 (8B)
//    -> k_l1 inner loop does ONE 8B gather from an 8MB table (was 16B+4B from
//       16MB+4MB tables): fewer streams, higher L2 hit rate.
//  - h2d stored as packed bf16x2 (4B) -> k_l2 gathers from a 4MB, L2-resident
//    table.
//  - k_bincount saves per-block bin counts (bh) so k_binscatter skips its
//    re-histogram pass.
//  - edge loops unrolled x2 for memory-level parallelism.

typedef unsigned int u32;

#define BSHIFT 11            // 2048 nodes per bucket
#define BNODES 2048
#define MAXNB 512            // max buckets supported (N <= 2^20)
#define EPB 16384            // edges per block in binning kernels

__device__ __forceinline__ u32 pack_bf16(float a, float b) {  // RTN
    u32 ua = __float_as_uint(a), ub = __float_as_uint(b);
    ua += 0x7FFFu + ((ua >> 16) & 1u);
    ub += 0x7FFFu + ((ub >> 16) & 1u);
    return (ua >> 16) | (ub & 0xFFFF0000u);
}
__device__ __forceinline__ float bf_lo(u32 p) { return __uint_as_float(p << 16); }
__device__ __forceinline__ float bf_hi(u32 p) { return __uint_as_float(p & 0xFFFF0000u); }

// ---- Phase A1: count edges per bucket; save per-block counts to bh ----
__global__ void k_bincount(const int* __restrict__ dst, int E, int NB,
                           u32* __restrict__ bucketTotal, u32* __restrict__ bh) {
    __shared__ u32 h[MAXNB];
    const int tid = threadIdx.x;
    for (int j = tid; j < MAXNB; j += 256) h[j] = 0;
    __syncthreads();
    const int start = blockIdx.x * EPB;
    const int end = min(start + EPB, E);
    for (int e = start + tid; e < end; e += 256)
        atomicAdd(&h[((u32)dst[e]) >> BSHIFT], 1u);
    __syncthreads();
    u32* bhrow = bh + (size_t)blockIdx.x * MAXNB;
    for (int j = tid; j < NB; j += 256) {
        u32 c = h[j];
        bhrow[j] = c;
        if (c) atomicAdd(&bucketTotal[j], c);
    }
}

// ---- Phase A2: exclusive scan of bucket totals (single block) ----
__global__ void k_bucketscan(const u32* __restrict__ bucketTotal,
                             u32* __restrict__ bucketBase,
                             u32* __restrict__ cursor, int NB, int E) {
    __shared__ u32 s[MAXNB];
    const int tid = threadIdx.x;  // 512 threads
    u32 v = (tid < NB) ? bucketTotal[tid] : 0u;
    s[tid] = v;
    __syncthreads();
    for (int d = 1; d < MAXNB; d <<= 1) {
        u32 t = (tid >= d) ? s[tid - d] : 0u;
        __syncthreads();
        s[tid] += t;
        __syncthreads();
    }
    u32 excl = s[tid] - v;
    if (tid < NB) { bucketBase[tid] = excl; cursor[tid] = excl; }
    if (tid == 0) bucketBase[NB] = (u32)E;
}

// ---- Phase A3: scatter edges into bucket-grouped records ----
// rec = src | (dstLocal << 20)   (src < 2^20, dstLocal < 2^11)
__global__ void k_binscatter(const int* __restrict__ src, const int* __restrict__ dst,
                             int E, int NB, u32* __restrict__ cursor,
                             const u32* __restrict__ bh, u32* __restrict__ rec) {
    __shared__ u32 h[MAXNB];
    const int tid = threadIdx.x;
    const u32* bhrow = bh + (size_t)blockIdx.x * MAXNB;
    for (int j = tid; j < MAXNB; j += 256) h[j] = 0;
    __syncthreads();
    for (int j = tid; j < NB; j += 256) {
        u32 c = bhrow[j];
        if (c) h[j] = atomicAdd(&cursor[j], c);
    }
    __syncthreads();
    const int start = blockIdx.x * EPB;
    const int end = min(start + EPB, E);
    for (int e = start + tid; e < end; e += 256) {
        u32 d = (u32)dst[e];
        u32 b = d >> BSHIFT;
        u32 slot = atomicAdd(&h[b], 1u);
        rec[slot] = ((u32)src[e]) | ((d & (BNODES - 1u)) << 20);
    }
}

// ---- Phase C: per-bucket degree -> dinv, and xd = x*dinv packed bf16x4 ----
__global__ void k_deg(const u32* __restrict__ rec, const u32* __restrict__ bucketBase,
                      const float4* __restrict__ x,
                      float* __restrict__ dinv, uint2* __restrict__ xd, int N) {
    __shared__ u32 deg[BNODES];
    const int tid = threadIdx.x;  // 512
    const int b = blockIdx.x;
    for (int j = tid; j < BNODES; j += 512) deg[j] = 0;
    __syncthreads();
    const u32 s0 = bucketBase[b], s1 = bucketBase[b + 1];
    for (u32 i = s0 + tid; i < s1; i += 512)
        atomicAdd(&deg[rec[i] >> 20], 1u);
    __syncthreads();
    const int nodeBase = b << BSHIFT;
    for (int n = tid; n < BNODES; n += 512) {
        int gn = nodeBase + n;
        if (gn < N) {
            float d = rsqrtf((float)(deg[n] + 1u));
            dinv[gn] = d;
            float4 xi = x[gn];
            xd[gn] = make_uint2(pack_bf16(xi.x * d, xi.y * d),
                                pack_bf16(xi.z * d, xi.w * d));
        }
    }
}

// ---- Phase D: layer-1 aggregate (LDS) + fused W1/relu/W2 -> h2 (bf16x2) ----
__global__ void k_l1(const u32* __restrict__ rec, const u32* __restrict__ bucketBase,
                     const float* __restrict__ dinv, const uint2* __restrict__ xd,
                     const float* __restrict__ W1, const float* __restrict__ b1,
                     const float* __restrict__ W2,
                     u32* __restrict__ h2, int N) {
    __shared__ float agg[BNODES * 4];
    const int tid = threadIdx.x;  // 1024
    const int b = blockIdx.x;
    for (int j = tid; j < BNODES * 4; j += 1024) agg[j] = 0.f;
    __syncthreads();
    const u32 s0 = bucketBase[b], s1 = bucketBase[b + 1];

#define L1_EDGE(I) do {                                   \
        u32 r = rec[I];                                   \
        u32 s = r & 0xFFFFFu;                             \
        float* p = &agg[(r >> 20) * 4];                   \
        uint2 v = xd[s];                                  \
        atomicAdd(p + 0, bf_lo(v.x));                     \
        atomicAdd(p + 1, bf_hi(v.x));                     \
        atomicAdd(p + 2, bf_lo(v.y));                     \
        atomicAdd(p + 3, bf_hi(v.y));                     \
    } while (0)

    u32 i = s0 + tid;
    for (; i + 1024 < s1; i += 2048) { L1_EDGE(i); L1_EDGE(i + 1024); }
    if (i < s1) L1_EDGE(i);
#undef L1_EDGE
    __syncthreads();

    const int nodeBase = b << BSHIFT;
    for (int n = tid; n < BNODES; n += 1024) {
        int gn = nodeBase + n;
        if (gn >= N) continue;
        float di = dinv[gn];
        uint2 xs = xd[gn];  // self term already scaled by dinv
        float ax = (bf_lo(xs.x) + agg[n * 4 + 0]) * di;
        float ay = (bf_hi(xs.x) + agg[n * 4 + 1]) * di;
        float az = (bf_lo(xs.y) + agg[n * 4 + 2]) * di;
        float aw = (bf_hi(xs.y) + agg[n * 4 + 3]) * di;
        float g0 = 0.f, g1 = 0.f;
#pragma unroll
        for (int k = 0; k < 16; ++k) {
            float h = ax * W1[k] + ay * W1[16 + k] + az * W1[32 + k] + aw * W1[48 + k] + b1[k];
            h = fmaxf(h, 0.f);
            g0 += h * W2[2 * k];
            g1 += h * W2[2 * k + 1];
        }
        h2[gn] = pack_bf16(g0 * di, g1 * di);
    }
}

// ---- Phase E: layer-2 aggregate (LDS) + fused log_softmax ----
__global__ void k_l2(const u32* __restrict__ rec, const u32* __restrict__ bucketBase,
                     const float* __restrict__ dinv, const u32* __restrict__ h2,
                     const float* __restrict__ b2, float2* __restrict__ out, int N) {
    __shared__ float agg[BNODES * 2];
    const int tid = threadIdx.x;  // 1024
    const int b = blockIdx.x;
    for (int j = tid; j < BNODES * 2; j += 1024) agg[j] = 0.f;
    __syncthreads();
    const u32 s0 = bucketBase[b], s1 = bucketBase[b + 1];

#define L2_EDGE(I) do {                                   \
        u32 r = rec[I];                                   \
        u32 s = r & 0xFFFFFu;                             \
        float* p = &agg[(r >> 20) * 2];                   \
        u32 v = h2[s];                                    \
        atomicAdd(p + 0, bf_lo(v));                       \
        atomicAdd(p + 1, bf_hi(v));                       \
    } while (0)

    u32 i = s0 + tid;
    for (; i + 1024 < s1; i += 2048) { L2_EDGE(i); L2_EDGE(i + 1024); }
    if (i < s1) L2_EDGE(i);
#undef L2_EDGE
    __syncthreads();

    const int nodeBase = b << BSHIFT;
    for (int n = tid; n < BNODES; n += 1024) {
        int gn = nodeBase + n;
        if (gn >= N) continue;
        float di = dinv[gn];
        u32 self = h2[gn];
        float g0 = (bf_lo(self) + agg[n * 2 + 0]) * di + b2[0];
        float g1 = (bf_hi(self) + agg[n * 2 + 1]) * di + b2[1];
        float m = fmaxf(g0, g1);
        float l = m + logf(expf(g0 - m) + expf(g1 - m));
        out[gn] = make_float2(g0 - l, g1 - l);
    }
}

extern "C" void kernel_launch(void* const* d_in, const int* in_sizes, int n_in,
                              void* d_out, int out_size, void* d_ws, size_t ws_size,
                              hipStream_t stream) {
    const float* x  = (const float*)d_in[0];
    const int*   ei = (const int*)d_in[1];   // [2, E] int32: src row then dst row
    const float* W1 = (const float*)d_in[3];
    const float* b1 = (const float*)d_in[4];
    const float* W2 = (const float*)d_in[5];
    const float* b2 = (const float*)d_in[6];

    const int N = in_sizes[0] / 4;
    const int E = in_sizes[1] / 2;
    const int* src = ei;
    const int* dst = ei + E;
    const int NB = (N + BNODES - 1) >> BSHIFT;  // 489 for N=1e6
    const int gA = (E + EPB - 1) / EPB;         // 245

    // Workspace (bytes):
    //   rec  [E u32]      @ 0          (16 MB)
    //   dinv [N f32]      @ 4E         (4 MB)
    //   xd   [N uint2]    @ 4E+4N      (8 MB)  x*dinv packed bf16x4
    //   h2   [N u32]      @ 4E+12N     (4 MB)  h2*dinv packed bf16x2
    //   meta              @ 4E+16N     bucketTotal[512] | bucketBase[513] |
    //                                  cursor[513] | bh[gA*512]
    char* w = (char*)d_ws;
    u32*   rec  = (u32*)(w);
    float* dinv = (float*)(w + 4 * (size_t)E);
    uint2* xd   = (uint2*)(w + 4 * (size_t)E + 4 * (size_t)N);
    u32*   h2   = (u32*)(w + 4 * (size_t)E + 12 * (size_t)N);
    u32*   meta = (u32*)(w + 4 * (size_t)E + 16 * (size_t)N);
    u32*   bucketTotal = meta;
    u32*   bucketBase  = meta + MAXNB;
    u32*   cursor      = meta + MAXNB + MAXNB + 1;
    u32*   bh          = meta + 3 * MAXNB + 2;

    hipMemsetAsync(bucketTotal, 0, sizeof(u32) * (size_t)NB, stream);
    k_bincount<<<gA, 256, 0, stream>>>(dst, E, NB, bucketTotal, bh);
    k_bucketscan<<<1, MAXNB, 0, stream>>>(bucketTotal, bucketBase, cursor, NB, E);
    k_binscatter<<<gA, 256, 0, stream>>>(src, dst, E, NB, cursor, bh, rec);
    k_deg<<<NB, 512, 0, stream>>>(rec, bucketBase, (const float4*)x, dinv, xd, N);
    k_l1<<<NB, 1024, 0, stream>>>(rec, bucketBase, dinv, xd, W1, b1, W2, h2, N);
    k_l2<<<NB, 1024, 0, stream>>>(rec, bucketBase, dinv, h2, b2, (float2*)d_out, N);
}

// Round 8
// 313.373 us; speedup vs baseline: 4.7605x; 1.0600x over previous
//
#include <hip/hip_runtime.h>

// 2-layer GCN via bucketed counting-sort aggregation with LDS accumulators.
// Round-8 change vs round-7: sort key extended from dstBucket to
// (dstBucket, srcHalf) -> within each dst bucket, edges whose src is in the
// lower half of the node range come first. Each half's gather working set
// (xd slice) is 4 MB = one XCD's L2, so the random xd[src] gathers in k_l1
// become mostly L2 hits. Aggregation kernels are unchanged; they just use
// the range [base[2b], base[2b+2]).

typedef unsigned int u32;

#define BSHIFT 11            // 2048 nodes per bucket
#define BNODES 2048
#define MAXBINS 1024         // 2*NB must fit; supports N <= 2^20
#define EPB 16384            // edges per block in binning kernels

__device__ __forceinline__ u32 pack_bf16(float a, float b) {  // RTN
    u32 ua = __float_as_uint(a), ub = __float_as_uint(b);
    ua += 0x7FFFu + ((ua >> 16) & 1u);
    ub += 0x7FFFu + ((ub >> 16) & 1u);
    return (ua >> 16) | (ub & 0xFFFF0000u);
}
__device__ __forceinline__ float bf_lo(u32 p) { return __uint_as_float(p << 16); }
__device__ __forceinline__ float bf_hi(u32 p) { return __uint_as_float(p & 0xFFFF0000u); }

// ---- A1: count edges per (bucket, srcHalf) bin; save per-block counts ----
__global__ void k_bincount(const int* __restrict__ src, const int* __restrict__ dst,
                           int E, int NBINS, u32 HALF,
                           u32* __restrict__ binTotal, u32* __restrict__ bh) {
    __shared__ u32 h[MAXBINS];
    const int tid = threadIdx.x;
    for (int j = tid; j < MAXBINS; j += 256) h[j] = 0;
    __syncthreads();
    const int start = blockIdx.x * EPB;
    const int end = min(start + EPB, E);
    for (int e = start + tid; e < end; e += 256) {
        u32 d = (u32)dst[e];
        u32 b = ((d >> BSHIFT) << 1) | ((u32)src[e] >= HALF ? 1u : 0u);
        atomicAdd(&h[b], 1u);
    }
    __syncthreads();
    u32* bhrow = bh + (size_t)blockIdx.x * MAXBINS;
    for (int j = tid; j < NBINS; j += 256) {
        u32 c = h[j];
        bhrow[j] = c;
        if (c) atomicAdd(&binTotal[j], c);
    }
}

// ---- A2: exclusive scan of bin totals (single 1024-thread block) ----
__global__ void k_binscan(const u32* __restrict__ binTotal,
                          u32* __restrict__ binBase,
                          u32* __restrict__ cursor, int NBINS, int E) {
    __shared__ u32 s[MAXBINS];
    const int tid = threadIdx.x;  // 1024
    u32 v = (tid < NBINS) ? binTotal[tid] : 0u;
    s[tid] = v;
    __syncthreads();
    for (int d = 1; d < MAXBINS; d <<= 1) {
        u32 t = (tid >= d) ? s[tid - d] : 0u;
        __syncthreads();
        s[tid] += t;
        __syncthreads();
    }
    u32 excl = s[tid] - v;
    if (tid < NBINS) { binBase[tid] = excl; cursor[tid] = excl; }
    if (tid == 0) binBase[NBINS] = (u32)E;
}

// ---- A3: scatter edges into bin-grouped records ----
// rec = src | (dstLocal << 20)   (src < 2^20, dstLocal < 2^11)
__global__ void k_binscatter(const int* __restrict__ src, const int* __restrict__ dst,
                             int E, int NBINS, u32 HALF, u32* __restrict__ cursor,
                             const u32* __restrict__ bh, u32* __restrict__ rec) {
    __shared__ u32 h[MAXBINS];
    const int tid = threadIdx.x;
    const u32* bhrow = bh + (size_t)blockIdx.x * MAXBINS;
    for (int j = tid; j < MAXBINS; j += 256) h[j] = 0;
    __syncthreads();
    for (int j = tid; j < NBINS; j += 256) {
        u32 c = bhrow[j];
        if (c) h[j] = atomicAdd(&cursor[j], c);
    }
    __syncthreads();
    const int start = blockIdx.x * EPB;
    const int end = min(start + EPB, E);
    for (int e = start + tid; e < end; e += 256) {
        u32 d = (u32)dst[e];
        u32 sv = (u32)src[e];
        u32 b = ((d >> BSHIFT) << 1) | (sv >= HALF ? 1u : 0u);
        u32 slot = atomicAdd(&h[b], 1u);
        rec[slot] = sv | ((d & (BNODES - 1u)) << 20);
    }
}

// ---- C: per-bucket degree -> dinv, and xd = x*dinv packed bf16x4 ----
__global__ void k_deg(const u32* __restrict__ rec, const u32* __restrict__ binBase,
                      const float4* __restrict__ x,
                      float* __restrict__ dinv, uint2* __restrict__ xd, int N) {
    __shared__ u32 deg[BNODES];
    const int tid = threadIdx.x;  // 512
    const int b = blockIdx.x;
    for (int j = tid; j < BNODES; j += 512) deg[j] = 0;
    __syncthreads();
    const u32 s0 = binBase[2 * b], s1 = binBase[2 * b + 2];
    for (u32 i = s0 + tid; i < s1; i += 512)
        atomicAdd(&deg[rec[i] >> 20], 1u);
    __syncthreads();
    const int nodeBase = b << BSHIFT;
    for (int n = tid; n < BNODES; n += 512) {
        int gn = nodeBase + n;
        if (gn < N) {
            float d = rsqrtf((float)(deg[n] + 1u));
            dinv[gn] = d;
            float4 xi = x[gn];
            xd[gn] = make_uint2(pack_bf16(xi.x * d, xi.y * d),
                                pack_bf16(xi.z * d, xi.w * d));
        }
    }
}

// ---- D: layer-1 aggregate (LDS) + fused W1/relu/W2 -> h2 (bf16x2) ----
__global__ void k_l1(const u32* __restrict__ rec, const u32* __restrict__ binBase,
                     const float* __restrict__ dinv, const uint2* __restrict__ xd,
                     const float* __restrict__ W1, const float* __restrict__ b1,
                     const float* __restrict__ W2,
                     u32* __restrict__ h2, int N) {
    __shared__ float agg[BNODES * 4];
    const int tid = threadIdx.x;  // 1024
    const int b = blockIdx.x;
    for (int j = tid; j < BNODES * 4; j += 1024) agg[j] = 0.f;
    __syncthreads();
    const u32 s0 = binBase[2 * b], s1 = binBase[2 * b + 2];

#define L1_EDGE(I) do {                                   \
        u32 r = rec[I];                                   \
        u32 s = r & 0xFFFFFu;                             \
        float* p = &agg[(r >> 20) * 4];                   \
        uint2 v = xd[s];                                  \
        atomicAdd(p + 0, bf_lo(v.x));                     \
        atomicAdd(p + 1, bf_hi(v.x));                     \
        atomicAdd(p + 2, bf_lo(v.y));                     \
        atomicAdd(p + 3, bf_hi(v.y));                     \
    } while (0)

    u32 i = s0 + tid;
    for (; i + 1024 < s1; i += 2048) { L1_EDGE(i); L1_EDGE(i + 1024); }
    if (i < s1) L1_EDGE(i);
#undef L1_EDGE
    __syncthreads();

    const int nodeBase = b << BSHIFT;
    for (int n = tid; n < BNODES; n += 1024) {
        int gn = nodeBase + n;
        if (gn >= N) continue;
        float di = dinv[gn];
        uint2 xs = xd[gn];  // self term already scaled by dinv
        float ax = (bf_lo(xs.x) + agg[n * 4 + 0]) * di;
        float ay = (bf_hi(xs.x) + agg[n * 4 + 1]) * di;
        float az = (bf_lo(xs.y) + agg[n * 4 + 2]) * di;
        float aw = (bf_hi(xs.y) + agg[n * 4 + 3]) * di;
        float g0 = 0.f, g1 = 0.f;
#pragma unroll
        for (int k = 0; k < 16; ++k) {
            float h = ax * W1[k] + ay * W1[16 + k] + az * W1[32 + k] + aw * W1[48 + k] + b1[k];
            h = fmaxf(h, 0.f);
            g0 += h * W2[2 * k];
            g1 += h * W2[2 * k + 1];
        }
        h2[gn] = pack_bf16(g0 * di, g1 * di);
    }
}

// ---- E: layer-2 aggregate (LDS) + fused log_softmax ----
__global__ void k_l2(const u32* __restrict__ rec, const u32* __restrict__ binBase,
                     const float* __restrict__ dinv, const u32* __restrict__ h2,
                     const float* __restrict__ b2, float2* __restrict__ out, int N) {
    __shared__ float agg[BNODES * 2];
    const int tid = threadIdx.x;  // 1024
    const int b = blockIdx.x;
    for (int j = tid; j < BNODES * 2; j += 1024) agg[j] = 0.f;
    __syncthreads();
    const u32 s0 = binBase[2 * b], s1 = binBase[2 * b + 2];

#define L2_EDGE(I) do {                                   \
        u32 r = rec[I];                                   \
        u32 s = r & 0xFFFFFu;                             \
        float* p = &agg[(r >> 20) * 2];                   \
        u32 v = h2[s];                                    \
        atomicAdd(p + 0, bf_lo(v));                       \
        atomicAdd(p + 1, bf_hi(v));                       \
    } while (0)

    u32 i = s0 + tid;
    for (; i + 1024 < s1; i += 2048) { L2_EDGE(i); L2_EDGE(i + 1024); }
    if (i < s1) L2_EDGE(i);
#undef L2_EDGE
    __syncthreads();

    const int nodeBase = b << BSHIFT;
    for (int n = tid; n < BNODES; n += 1024) {
        int gn = nodeBase + n;
        if (gn >= N) continue;
        float di = dinv[gn];
        u32 self = h2[gn];
        float g0 = (bf_lo(self) + agg[n * 2 + 0]) * di + b2[0];
        float g1 = (bf_hi(self) + agg[n * 2 + 1]) * di + b2[1];
        float m = fmaxf(g0, g1);
        float l = m + logf(expf(g0 - m) + expf(g1 - m));
        out[gn] = make_float2(g0 - l, g1 - l);
    }
}

extern "C" void kernel_launch(void* const* d_in, const int* in_sizes, int n_in,
                              void* d_out, int out_size, void* d_ws, size_t ws_size,
                              hipStream_t stream) {
    const float* x  = (const float*)d_in[0];
    const int*   ei = (const int*)d_in[1];   // [2, E] int32: src row then dst row
    const float* W1 = (const float*)d_in[3];
    const float* b1 = (const float*)d_in[4];
    const float* W2 = (const float*)d_in[5];
    const float* b2 = (const float*)d_in[6];

    const int N = in_sizes[0] / 4;
    const int E = in_sizes[1] / 2;
    const int* src = ei;
    const int* dst = ei + E;
    const int NB = (N + BNODES - 1) >> BSHIFT;  // 489 for N=1e6
    const int NBINS = 2 * NB;                   // 978
    const u32 HALF = (u32)(N >> 1);
    const int gA = (E + EPB - 1) / EPB;         // 245

    // Workspace (bytes):
    //   rec  [E u32]      @ 0          (16 MB)
    //   dinv [N f32]      @ 4E         (4 MB)
    //   xd   [N uint2]    @ 4E+4N      (8 MB)  x*dinv packed bf16x4
    //   h2   [N u32]      @ 4E+12N     (4 MB)  h2*dinv packed bf16x2
    //   meta              @ 4E+16N     binTotal[1024] | binBase[1025] |
    //                                  cursor[1024] | bh[gA*1024]  (~1 MB)
    char* w = (char*)d_ws;
    u32*   rec  = (u32*)(w);
    float* dinv = (float*)(w + 4 * (size_t)E);
    uint2* xd   = (uint2*)(w + 4 * (size_t)E + 4 * (size_t)N);
    u32*   h2   = (u32*)(w + 4 * (size_t)E + 12 * (size_t)N);
    u32*   meta = (u32*)(w + 4 * (size_t)E + 16 * (size_t)N);
    u32*   binTotal = meta;
    u32*   binBase  = meta + MAXBINS;
    u32*   cursor   = meta + 2 * MAXBINS + 1;
    u32*   bh       = meta + 3 * MAXBINS + 2;

    hipMemsetAsync(binTotal, 0, sizeof(u32) * (size_t)NBINS, stream);
    k_bincount<<<gA, 256, 0, stream>>>(src, dst, E, NBINS, HALF, binTotal, bh);
    k_binscan<<<1, MAXBINS, 0, stream>>>(binTotal, binBase, cursor, NBINS, E);
    k_binscatter<<<gA, 256, 0, stream>>>(src, dst, E, NBINS, HALF, cursor, bh, rec);
    k_deg<<<NB, 512, 0, stream>>>(rec, binBase, (const float4*)x, dinv, xd, N);
    k_l1<<<NB, 1024, 0, stream>>>(rec, binBase, dinv, xd, W1, b1, W2, h2, N);
    k_l2<<<NB, 1024, 0, stream>>>(rec, binBase, dinv, h2, b2, (float2*)d_out, N);
}